// Round 11
// baseline (303.698 us; speedup 1.0000x reference)
//
#include <hip/hip_runtime.h>

#define BB 32
#define SS 2048
#define DD 1024

typedef float f32x4 __attribute__((ext_vector_type(4)));

#if defined(__has_builtin)
#  if __has_builtin(__builtin_amdgcn_exp2f)
#    define EXP2F(x) __builtin_amdgcn_exp2f(x)
#  endif
#  if __has_builtin(__builtin_amdgcn_rcpf)
#    define RCPF(x) __builtin_amdgcn_rcpf(x)
#  endif
#endif
#ifndef EXP2F
#  define EXP2F(x) exp2f(x)
#endif
#ifndef RCPF
#  define RCPF(x) (1.0f / (x))
#endif

#define LOG2E 1.44269504088896340736f

__device__ __forceinline__ float fast_tanh(float x) {
    x = fminf(fmaxf(x, -20.0f), 20.0f);
    float e = EXP2F(x * (2.0f * LOG2E));
    return (e - 1.0f) * RCPF(e + 1.0f);
}

__device__ __forceinline__ f32x4 ntload4(const float* p) {
    return __builtin_nontemporal_load((const f32x4*)p);
}

// ---------------- K1: dec_feature = dec_hidden @ W^T + b; zero ctx/done ----------------
// R5-proven verbatim (8192-block full-width beats all low-width tiled variants).
__global__ __launch_bounds__(256) void k_decfeat(
    const float* __restrict__ dh, const float* __restrict__ W,
    const float* __restrict__ bd, float* __restrict__ df,
    float* __restrict__ ctx, int* __restrict__ done) {
    if (blockIdx.x < BB) {
        f32x4 z = {0.f, 0.f, 0.f, 0.f};
        ((f32x4*)ctx)[blockIdx.x * 256 + threadIdx.x] = z;
        if (threadIdx.x == 0) done[blockIdx.x] = 0;
    }
    int wave = threadIdx.x >> 6;
    int lane = threadIdx.x & 63;
    int o = blockIdx.x * 4 + wave;          // 0 .. 32767
    int b = o >> 10, i = o & 1023;
    const float4* wrow = (const float4*)(W + (size_t)i * DD);
    const float4* drow = (const float4*)(dh + (size_t)b * DD);
    float acc = 0.0f;
#pragma unroll
    for (int r = 0; r < 4; ++r) {
        float4 w4 = wrow[lane + 64 * r];
        float4 d4 = drow[lane + 64 * r];
        acc += w4.x * d4.x + w4.y * d4.y + w4.z * d4.z + w4.w * d4.w;
    }
#pragma unroll
    for (int off = 32; off; off >>= 1) acc += __shfl_down(acc, off, 64);
    if (lane == 0) df[o] = acc + bd[i];
}

// ---------------- F: fused score + context + last-block finalize ----------------
// block = (b, ch). Phase A: EM = exp(score)*mask for own 64 rows (proven),
// written unnormalized to attn; chunk-sum to unique address. Phase B: stream
// enc_output chunk, spread atomicAdd into ctx. Epilogue: 32nd finisher per b
// normalizes attn, writes covnew, scales ctx (overlapped, no extra dispatch).
__global__ __launch_bounds__(256) void k_fused(
    const float* __restrict__ ef, const float* __restrict__ df,
    const float* __restrict__ cov, const float* __restrict__ v,
    const float* __restrict__ wc, const float* __restrict__ mask,
    const float* __restrict__ eo, float* __restrict__ attn,
    float* __restrict__ covnew, float* __restrict__ sum_part,
    float* __restrict__ ctx, int* __restrict__ done) {
    int b = blockIdx.x >> 5, ch = blockIdx.x & 31;
    int s0 = ch * 64;
    int t = threadIdx.x;
    int lane = t & 63, wave = t >> 6;
    float4 v4 = ((const float4*)v)[t];
    float4 w4 = ((const float4*)wc)[t];
    float4 d4 = ((const float4*)(df + (size_t)b * DD))[t];
    __shared__ float als[64];
    __shared__ float red[4][8];
    // ---- Phase A: scores for 64 rows, 8 sub-tiles of 8 ----
    for (int sub = 0; sub < 8; ++sub) {
        int ss0 = s0 + sub * 8;
        float part[8];
#pragma unroll
        for (int k = 0; k < 8; ++k) {
            int s = ss0 + k;
            float c = cov[b * SS + s];
            f32x4 e4 = ntload4(ef + ((size_t)b * SS + s) * DD + t * 4);
            float t0 = fast_tanh(e4.x + d4.x + c * w4.x);
            float t1 = fast_tanh(e4.y + d4.y + c * w4.y);
            float t2 = fast_tanh(e4.z + d4.z + c * w4.z);
            float t3 = fast_tanh(e4.w + d4.w + c * w4.w);
            part[k] = v4.x * t0 + v4.y * t1 + v4.z * t2 + v4.w * t3;
        }
#pragma unroll
        for (int k = 0; k < 8; ++k) {
            float p = part[k];
#pragma unroll
            for (int off = 32; off; off >>= 1) p += __shfl_down(p, off, 64);
            if (lane == 0) red[wave][k] = p;
        }
        __syncthreads();
        if (t < 8) {
            float sc = red[0][t] + red[1][t] + red[2][t] + red[3][t];
            float em = EXP2F(sc * LOG2E) * mask[b * SS + ss0 + t];
            attn[b * SS + ss0 + t] = em;      // unnormalized for now
            als[sub * 8 + t] = em;
        }
        __syncthreads();
    }
    // ---- chunk sum to unique address ----
    if (t < 64) {
        float s = als[t];
#pragma unroll
        for (int off = 32; off; off >>= 1) s += __shfl_down(s, off, 64);
        if (t == 0) sum_part[b * 32 + ch] = s;
    }
    // ---- Phase B: stream enc_output chunk ----
    const float* base = eo + ((size_t)b * SS + s0) * DD;
    f32x4 acc = {0.f, 0.f, 0.f, 0.f};
#pragma unroll 8
    for (int k = 0; k < 64; ++k) {
        f32x4 e4 = ntload4(base + (size_t)k * DD + t * 4);
        acc += als[k] * e4;
    }
    float* cp = ctx + (size_t)b * DD + t * 4;
    atomicAdd(cp + 0, acc.x);
    atomicAdd(cp + 1, acc.y);
    atomicAdd(cp + 2, acc.z);
    atomicAdd(cp + 3, acc.w);
    // ---- last-block finalize for this b ----
    __threadfence();
    __shared__ int lastFlag;
    if (t == 0) lastFlag = (atomicAdd(done + b, 1) == 31);
    __syncthreads();
    if (!lastFlag) return;
    __threadfence();
    __shared__ float invs;
    if (t < 32) {
        float s = sum_part[b * 32 + t];
#pragma unroll
        for (int off = 16; off; off >>= 1) s += __shfl_down(s, off, 32);
        if (t == 0) invs = RCPF(s);
    }
    __syncthreads();
    float inv = invs;
#pragma unroll
    for (int k = 0; k < 8; ++k) {
        int s = t + 256 * k;
        float a = attn[b * SS + s] * inv;
        attn[b * SS + s] = a;
        covnew[b * SS + s] = cov[b * SS + s] + a;
    }
    f32x4* cp4 = (f32x4*)(ctx + (size_t)b * DD);
    cp4[t] = cp4[t] * inv;
}

extern "C" void kernel_launch(void* const* d_in, const int* in_sizes, int n_in,
                              void* d_out, int out_size, void* d_ws, size_t ws_size,
                              hipStream_t stream) {
    const float* dec_hidden  = (const float*)d_in[0];
    const float* enc_output  = (const float*)d_in[1];
    const float* enc_feature = (const float*)d_in[2];
    const float* enc_mask    = (const float*)d_in[3];
    // d_in[4] = sec_attn (unused by reference outputs)
    const float* coverage    = (const float*)d_in[5];
    const float* W_dec       = (const float*)d_in[6];
    const float* b_dec       = (const float*)d_in[7];
    const float* v           = (const float*)d_in[8];
    const float* w_cov       = (const float*)d_in[9];

    float* ctx    = (float*)d_out;                     // [B, DIM]   32768
    float* attn   = (float*)d_out + BB * DD;           // [B, S]     65536
    float* covnew = (float*)d_out + BB * DD + BB * SS; // [B, S]     65536

    char* ws = (char*)d_ws;
    float* df       = (float*)(ws);                    // 128 KiB
    float* sum_part = (float*)(ws + 131072);           // 4 KiB
    int*   done     = (int*)(ws + 131072 + 4096);      // 128 B

    k_decfeat <<<8192,  256, 0, stream>>>(dec_hidden, W_dec, b_dec, df, ctx, done);
    k_fused   <<<BB*32, 256, 0, stream>>>(enc_feature, df, coverage, v, w_cov,
                                          enc_mask, enc_output, attn, covnew,
                                          sum_part, ctx, done);
}

// Round 12
// 98.687 us; speedup vs baseline: 3.0774x; 3.0774x over previous
//
#include <hip/hip_runtime.h>

#define BB 32
#define SS 2048
#define DD 1024

typedef float f32x4 __attribute__((ext_vector_type(4)));

#if defined(__has_builtin)
#  if __has_builtin(__builtin_amdgcn_exp2f)
#    define EXP2F(x) __builtin_amdgcn_exp2f(x)
#  endif
#  if __has_builtin(__builtin_amdgcn_rcpf)
#    define RCPF(x) __builtin_amdgcn_rcpf(x)
#  endif
#endif
#ifndef EXP2F
#  define EXP2F(x) exp2f(x)
#endif
#ifndef RCPF
#  define RCPF(x) (1.0f / (x))
#endif

#define LOG2E 1.44269504088896340736f

__device__ __forceinline__ float fast_tanh(float x) {
    x = fminf(fmaxf(x, -20.0f), 20.0f);
    float e = EXP2F(x * (2.0f * LOG2E));
    return (e - 1.0f) * RCPF(e + 1.0f);
}

__device__ __forceinline__ f32x4 ntload4(const float* p) {
    return __builtin_nontemporal_load((const f32x4*)p);
}

// ---------------- K1: dec_feature = dec_hidden @ W^T + b; zero ctx ----------------
// R5-proven verbatim (8192-block full-width beats all low-width tiled variants).
__global__ __launch_bounds__(256) void k_decfeat(
    const float* __restrict__ dh, const float* __restrict__ W,
    const float* __restrict__ bd, float* __restrict__ df,
    float* __restrict__ ctx) {
    if (blockIdx.x < BB) {
        f32x4 z = {0.f, 0.f, 0.f, 0.f};
        ((f32x4*)ctx)[blockIdx.x * 256 + threadIdx.x] = z;
    }
    int wave = threadIdx.x >> 6;
    int lane = threadIdx.x & 63;
    int o = blockIdx.x * 4 + wave;          // 0 .. 32767
    int b = o >> 10, i = o & 1023;
    const float4* wrow = (const float4*)(W + (size_t)i * DD);
    const float4* drow = (const float4*)(dh + (size_t)b * DD);
    float acc = 0.0f;
#pragma unroll
    for (int r = 0; r < 4; ++r) {
        float4 w4 = wrow[lane + 64 * r];
        float4 d4 = drow[lane + 64 * r];
        acc += w4.x * d4.x + w4.y * d4.y + w4.z * d4.z + w4.w * d4.w;
    }
#pragma unroll
    for (int off = 32; off; off >>= 1) acc += __shfl_down(acc, off, 64);
    if (lane == 0) df[o] = acc + bd[i];
}

// ---------------- F: fused score + context over one 64-row chunk ----------------
// block = (b, ch). Phase A: EM = exp(score)*mask for own 64 rows; NEW: row
// accumulation via LDS atomicAdd (ds_add_f32, <=4 waves/address) -> 3 barriers
// per block instead of 16. Phase B: stream enc_output chunk, spread atomicAdd
// into ctx (2048 lines, <=32 writers each). NO device-scope fences (R11 lesson).
__global__ __launch_bounds__(256) void k_fused(
    const float* __restrict__ ef, const float* __restrict__ df,
    const float* __restrict__ cov, const float* __restrict__ v,
    const float* __restrict__ wc, const float* __restrict__ mask,
    const float* __restrict__ eo, float* __restrict__ attn_un,
    float* __restrict__ sum_part, float* __restrict__ ctx) {
    int b = blockIdx.x >> 5, ch = blockIdx.x & 31;
    int s0 = ch * 64;
    int t = threadIdx.x;
    int lane = t & 63;
    float4 v4 = ((const float4*)v)[t];
    float4 w4 = ((const float4*)wc)[t];
    float4 d4 = ((const float4*)(df + (size_t)b * DD))[t];
    __shared__ float als[64];
    if (t < 64) als[t] = 0.0f;
    __syncthreads();
    // ---- Phase A: scores for 64 rows, 8 sub-tiles of 8, LDS-atomic combine ----
    for (int sub = 0; sub < 8; ++sub) {
        int ss0 = s0 + sub * 8;
        float part[8];
#pragma unroll
        for (int k = 0; k < 8; ++k) {
            int s = ss0 + k;
            float c = cov[b * SS + s];
            f32x4 e4 = ntload4(ef + ((size_t)b * SS + s) * DD + t * 4);
            float t0 = fast_tanh(e4.x + d4.x + c * w4.x);
            float t1 = fast_tanh(e4.y + d4.y + c * w4.y);
            float t2 = fast_tanh(e4.z + d4.z + c * w4.z);
            float t3 = fast_tanh(e4.w + d4.w + c * w4.w);
            part[k] = v4.x * t0 + v4.y * t1 + v4.z * t2 + v4.w * t3;
        }
#pragma unroll
        for (int k = 0; k < 8; ++k) {
            float p = part[k];
#pragma unroll
            for (int off = 32; off; off >>= 1) p += __shfl_down(p, off, 64);
            if (lane == 0) atomicAdd(&als[sub * 8 + k], p);
        }
    }
    __syncthreads();
    if (t < 64) {
        int s = s0 + t;
        float em = EXP2F(als[t] * LOG2E) * mask[b * SS + s];
        attn_un[b * SS + s] = em;             // unnormalized; finalize scales
        als[t] = em;
    }
    __syncthreads();
    // ---- chunk sum to unique address ----
    if (t < 64) {
        float s = als[t];
#pragma unroll
        for (int off = 32; off; off >>= 1) s += __shfl_down(s, off, 64);
        if (t == 0) sum_part[b * 32 + ch] = s;
    }
    // ---- Phase B: stream enc_output chunk ----
    const float* base = eo + ((size_t)b * SS + s0) * DD;
    f32x4 acc = {0.f, 0.f, 0.f, 0.f};
#pragma unroll 8
    for (int k = 0; k < 64; ++k) {
        f32x4 e4 = ntload4(base + (size_t)k * DD + t * 4);
        acc += als[k] * e4;
    }
    float* cp = ctx + (size_t)b * DD + t * 4;
    atomicAdd(cp + 0, acc.x);
    atomicAdd(cp + 1, acc.y);
    atomicAdd(cp + 2, acc.z);
    atomicAdd(cp + 3, acc.w);
}

// ---------------- K5: finalize — inv, scale ctx, write attn/covnew ----------------
// 256 blocks = 32 b x 8 dt. Reduces 32 chunk-sums (redundant x8, trivial),
// scales its ctx slice in place, normalizes its attn slice, writes covnew.
__global__ __launch_bounds__(256) void k_finalize(
    const float* __restrict__ sum_part, const float* __restrict__ cov,
    float* __restrict__ attn, float* __restrict__ covnew,
    float* __restrict__ ctx) {
    int b = blockIdx.x >> 3, dt = blockIdx.x & 7;
    int t = threadIdx.x;
    __shared__ float invs;
    if (t < 32) {
        float s = sum_part[b * 32 + t];
#pragma unroll
        for (int off = 16; off; off >>= 1) s += __shfl_down(s, off, 32);
        if (t == 0) invs = RCPF(s);
    }
    __syncthreads();
    float inv = invs;
    // attn + covnew: 256 positions of this (b, dt)
    int s = dt * 256 + t;
    float a = attn[b * SS + s] * inv;
    attn[b * SS + s] = a;
    covnew[b * SS + s] = cov[b * SS + s] + a;
    // ctx: 128 floats of this (b, dt)
    if (t < 128) {
        int d = dt * 128 + t;
        ctx[(size_t)b * DD + d] *= inv;
    }
}

extern "C" void kernel_launch(void* const* d_in, const int* in_sizes, int n_in,
                              void* d_out, int out_size, void* d_ws, size_t ws_size,
                              hipStream_t stream) {
    const float* dec_hidden  = (const float*)d_in[0];
    const float* enc_output  = (const float*)d_in[1];
    const float* enc_feature = (const float*)d_in[2];
    const float* enc_mask    = (const float*)d_in[3];
    // d_in[4] = sec_attn (unused by reference outputs)
    const float* coverage    = (const float*)d_in[5];
    const float* W_dec       = (const float*)d_in[6];
    const float* b_dec       = (const float*)d_in[7];
    const float* v           = (const float*)d_in[8];
    const float* w_cov       = (const float*)d_in[9];

    float* ctx    = (float*)d_out;                     // [B, DIM]   32768
    float* attn   = (float*)d_out + BB * DD;           // [B, S]     65536
    float* covnew = (float*)d_out + BB * DD + BB * SS; // [B, S]     65536

    char* ws = (char*)d_ws;
    float* df       = (float*)(ws);                    // 128 KiB
    float* sum_part = (float*)(ws + 131072);           // 4 KiB

    k_decfeat  <<<8192,  256, 0, stream>>>(dec_hidden, W_dec, b_dec, df, ctx);
    k_fused    <<<BB*32, 256, 0, stream>>>(enc_feature, df, coverage, v, w_cov,
                                           enc_mask, enc_output, attn, sum_part, ctx);
    k_finalize <<<BB*8,  256, 0, stream>>>(sum_part, coverage, attn, covnew, ctx);
}

// Round 13
// 96.248 us; speedup vs baseline: 3.1554x; 1.0253x over previous
//
#include <hip/hip_runtime.h>

#define BB 32
#define SS 2048
#define DD 1024

typedef float f32x4 __attribute__((ext_vector_type(4)));

#if defined(__has_builtin)
#  if __has_builtin(__builtin_amdgcn_exp2f)
#    define EXP2F(x) __builtin_amdgcn_exp2f(x)
#  endif
#  if __has_builtin(__builtin_amdgcn_rcpf)
#    define RCPF(x) __builtin_amdgcn_rcpf(x)
#  endif
#endif
#ifndef EXP2F
#  define EXP2F(x) exp2f(x)
#endif
#ifndef RCPF
#  define RCPF(x) (1.0f / (x))
#endif

#define LOG2E 1.44269504088896340736f

__device__ __forceinline__ float fast_tanh(float x) {
    x = fminf(fmaxf(x, -20.0f), 20.0f);
    float e = EXP2F(x * (2.0f * LOG2E));
    return (e - 1.0f) * RCPF(e + 1.0f);
}

__device__ __forceinline__ f32x4 ntload4(const float* p) {
    return __builtin_nontemporal_load((const f32x4*)p);
}

// ---------------- K1: dec_feature = dec_hidden @ W^T + b; zero ctx ----------------
// ISOLATED TEST (R9 bundled it): 4x4 register-tiled; wave computes (4b)x(4i)
// tile; 8 loads / 16 f32x4-FMAs; logical traffic 256->64 MB; 512 blocks
// = 2 blocks/CU.
__global__ __launch_bounds__(256) void k_decfeat(
    const float* __restrict__ dh, const float* __restrict__ W,
    const float* __restrict__ bd, float* __restrict__ df,
    float* __restrict__ ctx) {
    if (blockIdx.x < BB) {
        f32x4 z = {0.f, 0.f, 0.f, 0.f};
        ((f32x4*)ctx)[blockIdx.x * 256 + threadIdx.x] = z;
    }
    int wave = threadIdx.x >> 6, lane = threadIdx.x & 63;
    int gw = blockIdx.x * 4 + wave;         // 0..2047
    int i0 = (gw >> 3) * 4;                 // 256 i-groups
    int b0 = (gw & 7) * 4;                  // 8 b-groups
    f32x4 acc[4][4];
#pragma unroll
    for (int j = 0; j < 4; ++j)
#pragma unroll
        for (int k = 0; k < 4; ++k) acc[j][k] = (f32x4){0.f, 0.f, 0.f, 0.f};
    for (int c = 0; c < 4; ++c) {
        int off = c * 256 + lane * 4;
        f32x4 w4[4], d4[4];
#pragma unroll
        for (int j = 0; j < 4; ++j)
            w4[j] = *(const f32x4*)(W + (size_t)(i0 + j) * DD + off);
#pragma unroll
        for (int k = 0; k < 4; ++k)
            d4[k] = *(const f32x4*)(dh + (size_t)(b0 + k) * DD + off);
#pragma unroll
        for (int j = 0; j < 4; ++j)
#pragma unroll
            for (int k = 0; k < 4; ++k) acc[j][k] += w4[j] * d4[k];
    }
#pragma unroll
    for (int j = 0; j < 4; ++j)
#pragma unroll
        for (int k = 0; k < 4; ++k) {
            f32x4 a = acc[j][k];
            float s = a.x + a.y + a.z + a.w;
#pragma unroll
            for (int o = 32; o; o >>= 1) s += __shfl_down(s, o, 64);
            if (lane == 0) df[(size_t)(b0 + k) * DD + i0 + j] = s + bd[i0 + j];
        }
}

// ---------------- F: fused score + context over one 64-row chunk ----------------
// R10-proven verbatim. block = (b, ch). Phase A: EM for own 64 rows (8-row
// tree reduce x8), unnormalized attn write + chunk-sum to unique address.
// Phase B: stream enc_output chunk, spread atomicAdd into ctx.
__global__ __launch_bounds__(256) void k_fused(
    const float* __restrict__ ef, const float* __restrict__ df,
    const float* __restrict__ cov, const float* __restrict__ v,
    const float* __restrict__ wc, const float* __restrict__ mask,
    const float* __restrict__ eo, float* __restrict__ attn_un,
    float* __restrict__ sum_part, float* __restrict__ ctx) {
    int b = blockIdx.x >> 5, ch = blockIdx.x & 31;
    int s0 = ch * 64;
    int t = threadIdx.x;
    int lane = t & 63, wave = t >> 6;
    float4 v4 = ((const float4*)v)[t];
    float4 w4 = ((const float4*)wc)[t];
    float4 d4 = ((const float4*)(df + (size_t)b * DD))[t];
    __shared__ float als[64];
    __shared__ float red[4][8];
    for (int sub = 0; sub < 8; ++sub) {
        int ss0 = s0 + sub * 8;
        float part[8];
#pragma unroll
        for (int k = 0; k < 8; ++k) {
            int s = ss0 + k;
            float c = cov[b * SS + s];
            f32x4 e4 = ntload4(ef + ((size_t)b * SS + s) * DD + t * 4);
            float t0 = fast_tanh(e4.x + d4.x + c * w4.x);
            float t1 = fast_tanh(e4.y + d4.y + c * w4.y);
            float t2 = fast_tanh(e4.z + d4.z + c * w4.z);
            float t3 = fast_tanh(e4.w + d4.w + c * w4.w);
            part[k] = v4.x * t0 + v4.y * t1 + v4.z * t2 + v4.w * t3;
        }
#pragma unroll
        for (int k = 0; k < 8; ++k) {
            float p = part[k];
#pragma unroll
            for (int off = 32; off; off >>= 1) p += __shfl_down(p, off, 64);
            if (lane == 0) red[wave][k] = p;
        }
        __syncthreads();
        if (t < 8) {
            float sc = red[0][t] + red[1][t] + red[2][t] + red[3][t];
            float em = EXP2F(sc * LOG2E) * mask[b * SS + ss0 + t];
            attn_un[b * SS + ss0 + t] = em;
            als[sub * 8 + t] = em;
        }
        __syncthreads();
    }
    if (t < 64) {
        float s = als[t];
#pragma unroll
        for (int off = 32; off; off >>= 1) s += __shfl_down(s, off, 64);
        if (t == 0) sum_part[b * 32 + ch] = s;
    }
    const float* base = eo + ((size_t)b * SS + s0) * DD;
    f32x4 acc = {0.f, 0.f, 0.f, 0.f};
#pragma unroll 8
    for (int k = 0; k < 64; ++k) {
        f32x4 e4 = ntload4(base + (size_t)k * DD + t * 4);
        acc += als[k] * e4;
    }
    float* cp = ctx + (size_t)b * DD + t * 4;
    atomicAdd(cp + 0, acc.x);
    atomicAdd(cp + 1, acc.y);
    atomicAdd(cp + 2, acc.z);
    atomicAdd(cp + 3, acc.w);
}

// ---------------- K5: finalize — inv, scale ctx, write attn/covnew ----------------
// R10-proven verbatim. 256 blocks = 32 b x 8 dt.
__global__ __launch_bounds__(256) void k_finalize(
    const float* __restrict__ sum_part, const float* __restrict__ cov,
    float* __restrict__ attn, float* __restrict__ covnew,
    float* __restrict__ ctx) {
    int b = blockIdx.x >> 3, dt = blockIdx.x & 7;
    int t = threadIdx.x;
    __shared__ float invs;
    if (t < 32) {
        float s = sum_part[b * 32 + t];
#pragma unroll
        for (int off = 16; off; off >>= 1) s += __shfl_down(s, off, 32);
        if (t == 0) invs = RCPF(s);
    }
    __syncthreads();
    float inv = invs;
    int s = dt * 256 + t;
    float a = attn[b * SS + s] * inv;
    attn[b * SS + s] = a;
    covnew[b * SS + s] = cov[b * SS + s] + a;
    if (t < 128) {
        int d = dt * 128 + t;
        ctx[(size_t)b * DD + d] *= inv;
    }
}

extern "C" void kernel_launch(void* const* d_in, const int* in_sizes, int n_in,
                              void* d_out, int out_size, void* d_ws, size_t ws_size,
                              hipStream_t stream) {
    const float* dec_hidden  = (const float*)d_in[0];
    const float* enc_output  = (const float*)d_in[1];
    const float* enc_feature = (const float*)d_in[2];
    const float* enc_mask    = (const float*)d_in[3];
    // d_in[4] = sec_attn (unused by reference outputs)
    const float* coverage    = (const float*)d_in[5];
    const float* W_dec       = (const float*)d_in[6];
    const float* b_dec       = (const float*)d_in[7];
    const float* v           = (const float*)d_in[8];
    const float* w_cov       = (const float*)d_in[9];

    float* ctx    = (float*)d_out;                     // [B, DIM]   32768
    float* attn   = (float*)d_out + BB * DD;           // [B, S]     65536
    float* covnew = (float*)d_out + BB * DD + BB * SS; // [B, S]     65536

    char* ws = (char*)d_ws;
    float* df       = (float*)(ws);                    // 128 KiB
    float* sum_part = (float*)(ws + 131072);           // 4 KiB

    k_decfeat  <<<512,   256, 0, stream>>>(dec_hidden, W_dec, b_dec, df, ctx);
    k_fused    <<<BB*32, 256, 0, stream>>>(enc_feature, df, coverage, v, w_cov,
                                           enc_mask, enc_output, attn, sum_part, ctx);
    k_finalize <<<BB*8,  256, 0, stream>>>(sum_part, coverage, attn, covnew, ctx);
}